// Round 1
// 863.380 us; speedup vs baseline: 1.0039x; 1.0039x over previous
//
#include <hip/hip_runtime.h>
#include <cstdint>

typedef __attribute__((ext_vector_type(8))) short short8;
typedef __attribute__((ext_vector_type(4))) float f32x4;

__device__ __forceinline__ ushort f2bf(float f) {
  union { float f; uint32_t u; } v; v.f = f;
  uint32_t u = v.u;
  return (ushort)((u + 0x7fffu + ((u >> 16) & 1u)) >> 16);  // RNE
}
__device__ __forceinline__ float bf2f(ushort h) {
  union { uint32_t u; float f; } v; v.u = ((uint32_t)h) << 16;
  return v.f;
}

// ---------------- prelude: conv1 (im2col MFMA) + weight transforms + zero g/out.
// blocks [0,1296): conv1; [1296,4496): w2t/w3t transform; 4496: zero g+out.
__global__ __launch_bounds__(256) void prelude_k(
    const float* __restrict__ x, const float* __restrict__ w1, const float* __restrict__ b1,
    const float* __restrict__ w2, const float* __restrict__ w3,
    ushort* __restrict__ o1, ushort* __restrict__ w2t, ushort* __restrict__ w3t,
    float* __restrict__ g, float* __restrict__ out) {
  __shared__ ushort sb[28 * 29];
  const int tid = threadIdx.x;
  const int bx = blockIdx.x;
  if (bx >= 1296) {
    if (bx < 4496) {
      int idx = (bx - 1296) * 256 + tid;
      if (idx < 204800) {  // 25*128*64
        int ic = idx & 63, oc = (idx >> 6) & 127, kk = idx >> 13;
        w2t[idx] = f2bf(w2[((size_t)oc * 64 + ic) * 25 + kk]);
      }
      // 25*256*128
      int ic = idx & 127, oc = (idx >> 7) & 255, kk = idx >> 15;
      w3t[idx] = f2bf(w3[((size_t)oc * 128 + ic) * 25 + kk]);
    } else {
      for (int i = tid; i < 8192; i += 256) g[i] = 0.f;
      for (int i = tid; i < 7168; i += 256) out[i] = 0.f;
    }
    return;
  }
  // conv1: tile 24x24 conv outputs (28x28 input), pooled 12x12x64 out
  const int b = bx / 81, rem = bx % 81, ty = rem / 9, tx = rem % 9;
  for (int i = tid; i < 784; i += 256) {
    int iy = i / 28, ix = i % 28;
    sb[iy * 29 + ix] = f2bf(x[((size_t)b * 220 + ty * 24 + iy) * 220 + tx * 24 + ix]);
  }
  __syncthreads();
  const int lane = tid & 63, wid = tid >> 6;
  const int m16 = lane & 15, qd = lane >> 4;
  short8 bfr[4];
#pragma unroll
  for (int n = 0; n < 4; n++) {
    union { ushort u[8]; short8 v; } t;
#pragma unroll
    for (int j = 0; j < 8; j++) {
      int k = qd * 8 + j;
      int kc = k < 25 ? k : 0;
      ushort val = f2bf(w1[(n * 16 + m16) * 25 + kc]);
      t.u[j] = (k < 25) ? val : (ushort)0;
    }
    bfr[n] = t.v;
  }
  int offs[8];
#pragma unroll
  for (int j = 0; j < 8; j++) {
    int k = qd * 8 + j;
    int kc = k < 25 ? k : 24;  // k>=25: B is zero, value irrelevant
    offs[j] = (kc / 5) * 29 + (kc % 5);
  }
  float bias[4];
#pragma unroll
  for (int n = 0; n < 4; n++) bias[n] = b1[n * 16 + m16];
  for (int gg = 0; gg < 9; gg++) {
    int gr = wid * 9 + gg;
    int wglob = gr * 4 + (m16 >> 2);
    int wy = wglob / 12, wx = wglob % 12;
    int py = wy * 2 + ((m16 >> 1) & 1), px = wx * 2 + (m16 & 1);
    int base = py * 29 + px;
    union { ushort u[8]; short8 v; } a;
#pragma unroll
    for (int j = 0; j < 8; j++) a.u[j] = sb[base + offs[j]];
    int wgd = gr * 4 + qd;
    int gy = ty * 12 + wgd / 12, gx = tx * 12 + wgd % 12;
    size_t oidx = (((size_t)b * 108 + gy) * 108 + gx) * 64;
#pragma unroll
    for (int n = 0; n < 4; n++) {
      f32x4 d = (f32x4){0.f, 0.f, 0.f, 0.f};
      d = __builtin_amdgcn_mfma_f32_16x16x32_bf16(a.v, bfr[n], d, 0, 0, 0);
      float mx = fmaxf(fmaxf(d[0], d[1]), fmaxf(d[2], d[3]));
      o1[oidx + n * 16 + m16] = f2bf(fmaxf(mx + bias[n], 0.f));
    }
  }
}

// ---------------- conv2/conv3: kn2row implicit-GEMM MFMA, fused bias+relu+pool
// Restructured: 2 batches per block; each wave = 64px x 64oc (ms=4 x ns=4).
// Wave wid: bh = wid>>1 (batch half), og = wid&1 (oc group of 64).
// Waves (0,2)/(1,3) read identical weight addresses -> L1 hits; LDS A-traffic
// per MFMA halves vs the 64px x 32oc layout.
template <int IC, int ICP, int OCT, int OCB, int INW, int POOLW>
__global__ __launch_bounds__(256) void conv_mfma(const ushort* __restrict__ in,
                                                 const ushort* __restrict__ wt,
                                                 const float* __restrict__ bias,
                                                 ushort* __restrict__ out) {
  constexpr int NPIX = 144;  // 12*12 input tile
  constexpr int PSTRIDE = OCB + 8;
  constexpr int LDSA = 2 * NPIX * ICP;
  constexpr int LDSP = 2 * 64 * PSTRIDE;
  constexpr int LDSN = (LDSA > LDSP) ? LDSA : LDSP;
  __shared__ ushort sm[LDSN];
  const int tid = threadIdx.x;
  const int wid = tid >> 6, lane = tid & 63;
  const int m16 = lane & 15, qd = lane >> 4;
  const int bh = wid >> 1, og = wid & 1;
  constexpr int OCSPLIT = OCT / OCB;
  const int bpair = blockIdx.z / OCSPLIT;
  const int ocblk = (blockIdx.z % OCSPLIT) * OCB;
  const int b0 = bpair * 2;
  const int ty = blockIdx.y, tx = blockIdx.x;
  {
    constexpr int C8 = IC / 8;
    for (int i = tid; i < 2 * NPIX * C8; i += 256) {
      int bb = i / (NPIX * C8), rem = i % (NPIX * C8);
      int px = rem / C8, c8 = rem % C8;
      int gy = ty * 8 + px / 12, gx = tx * 8 + px % 12;
      uint4 v = *(const uint4*)(in + (((size_t)(b0 + bb) * INW + gy) * INW + gx) * IC + c8 * 8);
      *(uint4*)&sm[(bb * NPIX + px) * ICP + c8 * 8] = v;
    }
  }
  __syncthreads();
  f32x4 acc[4][4];
#pragma unroll
  for (int i = 0; i < 4; i++)
#pragma unroll
    for (int j = 0; j < 4; j++) acc[i][j] = (f32x4){0.f, 0.f, 0.f, 0.f};
  int aoff[4];
#pragma unroll
  for (int ms = 0; ms < 4; ms++) {
    int p = ms * 16 + m16;
    aoff[ms] = (bh * NPIX + (p >> 3) * 12 + (p & 7)) * ICP + qd * 8;
  }
  const int woc0 = ocblk + og * 64 + m16;
  for (int ky = 0; ky < 5; ky++) {
#pragma unroll
    for (int kx = 0; kx < 5; kx++) {
      const int koff = (ky * 12 + kx) * ICP;
      const ushort* wp = wt + ((size_t)(ky * 5 + kx) * OCT + woc0) * IC + qd * 8;
#pragma unroll
      for (int ks = 0; ks < IC / 32; ks++) {
        short8 afr[4], bfr[4];
#pragma unroll
        for (int ms = 0; ms < 4; ms++)
          afr[ms] = *(const short8*)&sm[aoff[ms] + koff + ks * 32];
#pragma unroll
        for (int ns = 0; ns < 4; ns++)
          bfr[ns] = *(const short8*)(wp + ns * 16 * IC + ks * 32);
#pragma unroll
        for (int ms = 0; ms < 4; ms++)
#pragma unroll
          for (int ns = 0; ns < 4; ns++)
            acc[ms][ns] = __builtin_amdgcn_mfma_f32_16x16x32_bf16(afr[ms], bfr[ns], acc[ms][ns], 0, 0, 0);
      }
    }
  }
  __syncthreads();
#pragma unroll
  for (int ms = 0; ms < 4; ms++)
#pragma unroll
    for (int ns = 0; ns < 4; ns++) {
      int ocl = og * 64 + ns * 16 + m16;
      float bv = bias[ocblk + ocl];
#pragma unroll
      for (int r = 0; r < 4; r++) {
        int p = ms * 16 + qd * 4 + r;
        sm[(bh * 64 + p) * PSTRIDE + ocl] = f2bf(fmaxf(acc[ms][ns][r] + bv, 0.f));
      }
    }
  __syncthreads();
  constexpr int OC2 = OCB / 2;
  const int oc2 = tid % OC2, pst = tid / OC2;
  for (int pp = pst; pp < 32; pp += 256 / OC2) {
    int bb = pp >> 4, pl = pp & 15;
    int ppy = pl >> 2, ppx = pl & 3;
    int p00 = (ppy * 2) * 8 + ppx * 2;
    int oc = oc2 * 2;
    int base = bb * 64 * PSTRIDE;
    uint32_t v0 = *(const uint32_t*)&sm[base + p00 * PSTRIDE + oc];
    uint32_t v1 = *(const uint32_t*)&sm[base + (p00 + 1) * PSTRIDE + oc];
    uint32_t v2 = *(const uint32_t*)&sm[base + (p00 + 8) * PSTRIDE + oc];
    uint32_t v3 = *(const uint32_t*)&sm[base + (p00 + 9) * PSTRIDE + oc];
    float a0 = fmaxf(fmaxf(bf2f(v0 & 0xffff), bf2f(v1 & 0xffff)),
                     fmaxf(bf2f(v2 & 0xffff), bf2f(v3 & 0xffff)));
    float a1 = fmaxf(fmaxf(bf2f(v0 >> 16), bf2f(v1 >> 16)),
                     fmaxf(bf2f(v2 >> 16), bf2f(v3 >> 16)));
    uint32_t packed = ((uint32_t)f2bf(a1) << 16) | (uint32_t)f2bf(a0);
    int gy = ty * 4 + ppy, gx = tx * 4 + ppx;
    *(uint32_t*)&out[(((size_t)(b0 + bb) * POOLW + gy) * POOLW + gx) * OCT + ocblk + oc] = packed;
  }
}

// ---------------- transpose o3 NHWC -> NCHW-flat (for FC), bf16
__global__ void transpose_o3(const ushort* __restrict__ o3, ushort* __restrict__ flatT) {
  __shared__ ushort t[32][33];
  const int b = blockIdx.z;
  const int n0 = blockIdx.x * 32, c0 = blockIdx.y * 32;
  const int tid = threadIdx.x;
  {
    int cl = tid & 31, r = tid >> 5;
    for (int i = 0; i < 4; i++) {
      int nl = r + i * 8;
      t[nl][cl] = o3[((size_t)b * 576 + n0 + nl) * 256 + c0 + cl];
    }
  }
  __syncthreads();
  {
    int nl = tid & 31, r = tid >> 5;
    for (int i = 0; i < 4; i++) {
      int cl = r + i * 8;
      flatT[(size_t)b * 147456 + (c0 + cl) * 576 + n0 + nl] = t[nl][cl];
    }
  }
}

// ---------------- FC: g[16][512] = flat @ fcw^T, MFMA; A coalesced from flatT.
// grid (256 k-chunks, 2 j-blocks) = 512 blocks -> 2 blocks/CU for deeper
// HBM-load pipelining (fcw stream is the floor here).
__global__ void fc_mfma(const ushort* __restrict__ flatT, const float* __restrict__ fcw,
                        float* __restrict__ g) {
  const int tid = threadIdx.x;
  const int wid = tid >> 6, lane = tid & 63;
  const int m16 = lane & 15, qd = lane >> 4;
  const int jt = blockIdx.y * 256 + wid * 64;
  const int K0 = blockIdx.x * 576;
  f32x4 acc[4];
#pragma unroll
  for (int f = 0; f < 4; f++) acc[f] = (f32x4){0.f, 0.f, 0.f, 0.f};
  const ushort* ap = flatT + (size_t)m16 * 147456 + K0 + qd * 8;
  const float* bp = fcw + (size_t)(jt + m16) * 147456 + K0 + qd * 8;
#pragma unroll 2
  for (int ks = 0; ks < 18; ks++) {
    short8 a = *(const short8*)(ap + ks * 32);
#pragma unroll
    for (int f = 0; f < 4; f++) {
      const float* bpf = bp + (size_t)f * 16 * 147456 + ks * 32;
      float4 b0 = *(const float4*)bpf;
      float4 b1 = *(const float4*)(bpf + 4);
      short8 bb;
      bb[0] = (short)f2bf(b0.x); bb[1] = (short)f2bf(b0.y);
      bb[2] = (short)f2bf(b0.z); bb[3] = (short)f2bf(b0.w);
      bb[4] = (short)f2bf(b1.x); bb[5] = (short)f2bf(b1.y);
      bb[6] = (short)f2bf(b1.z); bb[7] = (short)f2bf(b1.w);
      acc[f] = __builtin_amdgcn_mfma_f32_16x16x32_bf16(a, bb, acc[f], 0, 0, 0);
    }
  }
  const int brow = qd * 4;
#pragma unroll
  for (int f = 0; f < 4; f++)
#pragma unroll
    for (int r = 0; r < 4; r++)
      atomicAdd(&g[(brow + r) * 512 + jt + f * 16 + m16], acc[f][r]);
}

// ---------------- scores (all heads): per-block q-slice prelude, then dot rows
template <int C>
__device__ __forceinline__ void score_head(const ushort* __restrict__ f,
                                           const float* __restrict__ aw,
                                           const float* __restrict__ ab,
                                           const float* __restrict__ g,
                                           const float* __restrict__ fcb,
                                           float* __restrict__ s, int N, int nblk, int b,
                                           float* sq, float* sp) {
  const int tid = threadIdx.x;
  constexpr int PARTS = 256 / C;
  constexpr int L = 512 / PARTS;
  {
    int c = tid % C, part = tid / C;
    const float* ar = aw + (size_t)c * 512 + part * L;
    const float* gr = g + b * 512 + part * L;
    const float* fb = fcb + part * L;
    float acc = 0.f;
#pragma unroll 8
    for (int j = 0; j < L; j++) acc += ar[j] * (gr[j] + fb[j]);
    sp[tid] = acc;
  }
  __syncthreads();
  if (tid < C) {
    float v = ab[tid];
#pragma unroll
    for (int p = 0; p < PARTS; p++) v += sp[tid + p * C];
    sq[tid] = v;
  }
  __syncthreads();
  int n = nblk * 256 + tid;
  if (n >= N) return;
  const ushort* fr = f + ((size_t)b * N + n) * C;
  float acc = 0.f;
#pragma unroll
  for (int c0 = 0; c0 < C; c0 += 8) {
    uint4 v = *(const uint4*)&fr[c0];
    uint32_t arr[4] = {v.x, v.y, v.z, v.w};
#pragma unroll
    for (int k = 0; k < 4; k++) {
      acc += bf2f(arr[k] & 0xffff) * sq[c0 + 2 * k];
      acc += bf2f(arr[k] >> 16) * sq[c0 + 2 * k + 1];
    }
  }
  s[(size_t)b * N + n] = acc;
}

__global__ void scores_all(const ushort* __restrict__ o1, const ushort* __restrict__ o2,
                           const ushort* __restrict__ o3, const float* __restrict__ g,
                           const float* __restrict__ fcb,
                           const float* __restrict__ aw1, const float* __restrict__ ab1,
                           const float* __restrict__ aw2, const float* __restrict__ ab2,
                           const float* __restrict__ aw3, const float* __restrict__ ab3,
                           float* __restrict__ s1, float* __restrict__ s2,
                           float* __restrict__ s3) {
  __shared__ float sq[256];
  __shared__ float sp[256];
  const int bx = blockIdx.x, b = blockIdx.y;
  if (bx < 46)      score_head<64>(o1, aw1, ab1, g, fcb, s1, 11664, bx, b, sq, sp);
  else if (bx < 57) score_head<128>(o2, aw2, ab2, g, fcb, s2, 2704, bx - 46, b, sq, sp);
  else              score_head<256>(o3, aw3, ab3, g, fcb, s3, 576, bx - 57, b, sq, sp);
}

// ---------------- softmax stats (all heads)
__global__ void stats_all(const float* __restrict__ s1, const float* __restrict__ s2,
                          const float* __restrict__ s3, float* __restrict__ st) {
  const int b = blockIdx.x, head = blockIdx.y, tid = threadIdx.x;
  const float* s; int N; float* stp;
  if (head == 0)      { s = s1; N = 11664; stp = st; }
  else if (head == 1) { s = s2; N = 2704;  stp = st + 32; }
  else                { s = s3; N = 576;   stp = st + 64; }
  const float* sb = s + (size_t)b * N;
  __shared__ float red[4];
  float m = -1e30f;
  for (int i = tid; i < N; i += 256) m = fmaxf(m, sb[i]);
  for (int o = 32; o; o >>= 1) m = fmaxf(m, __shfl_xor(m, o));
  if ((tid & 63) == 0) red[tid >> 6] = m;
  __syncthreads();
  m = fmaxf(fmaxf(red[0], red[1]), fmaxf(red[2], red[3]));
  __syncthreads();
  float l = 0.f;
  for (int i = tid; i < N; i += 256) l += __expf(sb[i] - m);
  for (int o = 32; o; o >>= 1) l += __shfl_xor(l, o);
  if ((tid & 63) == 0) red[tid >> 6] = l;
  __syncthreads();
  if (tid == 0) { stp[b * 2] = m; stp[b * 2 + 1] = red[0] + red[1] + red[2] + red[3]; }
}

// ---------------- weighted sum (all heads)
template <int C, int COFF, int CHUNK>
__device__ __forceinline__ void wsum_head(const ushort* __restrict__ f,
                                          const float* __restrict__ s,
                                          const float* __restrict__ st,
                                          float* __restrict__ out, int N, int nblk, int b) {
  const int tid = threadIdx.x;
  constexpr int S = 256 / C;
  const int c = tid % C, sub = tid / C;
  const float m = st[b * 2], rl = 1.f / st[b * 2 + 1];
  const float* sb = s + (size_t)b * N;
  const ushort* fb = f + (size_t)b * N * C;
  int n0 = nblk * CHUNK;
  int n1 = n0 + CHUNK; if (n1 > N) n1 = N;
  float acc = 0.f;
  for (int n = n0 + sub; n < n1; n += S) {
    float w = __expf(sb[n] - m);
    acc += w * bf2f(fb[(size_t)n * C + c]);
  }
  atomicAdd(&out[b * 448 + COFF + c], acc * rl);
}

__global__ void wsum_all(const ushort* __restrict__ o1, const ushort* __restrict__ o2,
                         const ushort* __restrict__ o3, const float* __restrict__ s1,
                         const float* __restrict__ s2, const float* __restrict__ s3,
                         const float* __restrict__ st, float* __restrict__ out) {
  const int bx = blockIdx.x, b = blockIdx.y;
  if (bx < 24)      wsum_head<64, 0, 486>(o1, s1, st, out, 11664, bx, b);
  else if (bx < 40) wsum_head<128, 64, 169>(o2, s2, st + 32, out, 2704, bx - 24, b);
  else              wsum_head<256, 192, 72>(o3, s3, st + 64, out, 576, bx - 40, b);
}

extern "C" void kernel_launch(void* const* d_in, const int* in_sizes, int n_in,
                              void* d_out, int out_size, void* d_ws, size_t ws_size,
                              hipStream_t stream) {
  const float* x   = (const float*)d_in[0];
  const float* w1  = (const float*)d_in[1];
  const float* b1  = (const float*)d_in[2];
  const float* w2  = (const float*)d_in[3];
  const float* b2  = (const float*)d_in[4];
  const float* w3  = (const float*)d_in[5];
  const float* b3  = (const float*)d_in[6];
  const float* fcw = (const float*)d_in[7];
  const float* fcb = (const float*)d_in[8];
  const float* aw1 = (const float*)d_in[9];
  const float* ab1 = (const float*)d_in[10];
  const float* aw2 = (const float*)d_in[11];
  const float* ab2 = (const float*)d_in[12];
  const float* aw3 = (const float*)d_in[13];
  const float* ab3 = (const float*)d_in[14];
  float* out = (float*)d_out;
  char* ws = (char*)d_ws;

  ushort* o1    = (ushort*)(ws + 0);         // 23887872
  ushort* o2    = (ushort*)(ws + 23887872);  // 11075584
  ushort* o3    = (ushort*)(ws + 34963456);  // 4718592
  ushort* flatT = (ushort*)(ws + 39682048);  // 4718592
  ushort* w2t   = (ushort*)(ws + 44400640);  // 409600
  ushort* w3t   = (ushort*)(ws + 44810240);  // 1638400
  float*  g     = (float*)(ws + 46448640);   // 32768
  float*  s1    = (float*)(ws + 46510080);   // 746496
  float*  s2    = (float*)(ws + 47256576);   // 173056
  float*  s3    = (float*)(ws + 47429632);   // 36864
  float*  st    = (float*)(ws + 47466496);   // 384

  prelude_k<<<4497, 256, 0, stream>>>(x, w1, b1, w2, w3, o1, w2t, w3t, g, out);
  // 2 batches/block: z = 8 batch-pairs * OCSPLIT
  conv_mfma<64, 72, 128, 128, 108, 52><<<dim3(13, 13, 8), 256, 0, stream>>>(o1, w2t, b2, o2);
  conv_mfma<128, 136, 256, 128, 52, 24><<<dim3(6, 6, 16), 256, 0, stream>>>(o2, w3t, b3, o3);
  transpose_o3<<<dim3(18, 8, 16), 256, 0, stream>>>(o3, flatT);
  fc_mfma<<<dim3(256, 2), 256, 0, stream>>>(flatT, fcw, g);
  scores_all<<<dim3(60, 16), 256, 0, stream>>>(o1, o2, o3, g, fcb, aw1, ab1, aw2, ab2,
                                               aw3, ab3, s1, s2, s3);
  stats_all<<<dim3(16, 3), 256, 0, stream>>>(s1, s2, s3, st);
  wsum_all<<<dim3(48, 16), 256, 0, stream>>>(o1, o2, o3, s1, s2, s3, st, out);
}

// Round 2
// 710.815 us; speedup vs baseline: 1.2194x; 1.2146x over previous
//
#include <hip/hip_runtime.h>
#include <cstdint>

typedef __attribute__((ext_vector_type(8))) short short8;
typedef __attribute__((ext_vector_type(4))) float f32x4;

__device__ __forceinline__ ushort f2bf(float f) {
  union { float f; uint32_t u; } v; v.f = f;
  uint32_t u = v.u;
  return (ushort)((u + 0x7fffu + ((u >> 16) & 1u)) >> 16);  // RNE
}
__device__ __forceinline__ float bf2f(ushort h) {
  union { uint32_t u; float f; } v; v.u = ((uint32_t)h) << 16;
  return v.f;
}

// ---------------- prelude: conv1 (im2col MFMA) + weight transforms + zero g/out.
// blocks [0,1296): conv1; [1296,4496): w2t/w3t transform; 4496: zero g+out.
// w2t/w3t are written in MFMA-fragment-linear order:
//   idx = (((kpos*(OCT/16) + fo)*(IC/32)) + ks)*512 + lane*8 + j
//   value = w[oc = fo*16 + (lane&15)][ic = ks*32 + (lane>>4)*8 + j][kpos]
// so conv_mfma's B-fragment load is one wave-coalesced 1KB read.
__global__ __launch_bounds__(256) void prelude_k(
    const float* __restrict__ x, const float* __restrict__ w1, const float* __restrict__ b1,
    const float* __restrict__ w2, const float* __restrict__ w3,
    ushort* __restrict__ o1, ushort* __restrict__ w2t, ushort* __restrict__ w3t,
    float* __restrict__ g, float* __restrict__ out) {
  __shared__ ushort sb[28 * 29];
  const int tid = threadIdx.x;
  const int bx = blockIdx.x;
  if (bx >= 1296) {
    if (bx < 4496) {
      int idx = (bx - 1296) * 256 + tid;
      if (idx < 204800) {  // 25 kpos * 8 frags * 2 ks * 512
        int j = idx & 7, lane = (idx >> 3) & 63, ks = (idx >> 9) & 1,
            fo = (idx >> 10) & 7, kpos = idx >> 13;
        int oc = fo * 16 + (lane & 15);
        int ic = ks * 32 + (lane >> 4) * 8 + j;
        w2t[idx] = f2bf(w2[((size_t)oc * 64 + ic) * 25 + kpos]);
      }
      {  // 25 kpos * 16 frags * 4 ks * 512 = 819200
        int j = idx & 7, lane = (idx >> 3) & 63, ks = (idx >> 9) & 3,
            fo = (idx >> 11) & 15, kpos = idx >> 15;
        int oc = fo * 16 + (lane & 15);
        int ic = ks * 32 + (lane >> 4) * 8 + j;
        w3t[idx] = f2bf(w3[((size_t)oc * 128 + ic) * 25 + kpos]);
      }
    } else {
      for (int i = tid; i < 8192; i += 256) g[i] = 0.f;
      for (int i = tid; i < 7168; i += 256) out[i] = 0.f;
    }
    return;
  }
  // conv1: tile 24x24 conv outputs (28x28 input), pooled 12x12x64 out
  const int b = bx / 81, rem = bx % 81, ty = rem / 9, tx = rem % 9;
  for (int i = tid; i < 784; i += 256) {
    int iy = i / 28, ix = i % 28;
    sb[iy * 29 + ix] = f2bf(x[((size_t)b * 220 + ty * 24 + iy) * 220 + tx * 24 + ix]);
  }
  __syncthreads();
  const int lane = tid & 63, wid = tid >> 6;
  const int m16 = lane & 15, qd = lane >> 4;
  short8 bfr[4];
#pragma unroll
  for (int n = 0; n < 4; n++) {
    union { ushort u[8]; short8 v; } t;
#pragma unroll
    for (int j = 0; j < 8; j++) {
      int k = qd * 8 + j;
      int kc = k < 25 ? k : 0;
      ushort val = f2bf(w1[(n * 16 + m16) * 25 + kc]);
      t.u[j] = (k < 25) ? val : (ushort)0;
    }
    bfr[n] = t.v;
  }
  int offs[8];
#pragma unroll
  for (int j = 0; j < 8; j++) {
    int k = qd * 8 + j;
    int kc = k < 25 ? k : 24;  // k>=25: B is zero, value irrelevant
    offs[j] = (kc / 5) * 29 + (kc % 5);
  }
  float bias[4];
#pragma unroll
  for (int n = 0; n < 4; n++) bias[n] = b1[n * 16 + m16];
  for (int gg = 0; gg < 9; gg++) {
    int gr = wid * 9 + gg;
    int wglob = gr * 4 + (m16 >> 2);
    int wy = wglob / 12, wx = wglob % 12;
    int py = wy * 2 + ((m16 >> 1) & 1), px = wx * 2 + (m16 & 1);
    int base = py * 29 + px;
    union { ushort u[8]; short8 v; } a;
#pragma unroll
    for (int j = 0; j < 8; j++) a.u[j] = sb[base + offs[j]];
    int wgd = gr * 4 + qd;
    int gy = ty * 12 + wgd / 12, gx = tx * 12 + wgd % 12;
    size_t oidx = (((size_t)b * 108 + gy) * 108 + gx) * 64;
#pragma unroll
    for (int n = 0; n < 4; n++) {
      f32x4 d = (f32x4){0.f, 0.f, 0.f, 0.f};
      d = __builtin_amdgcn_mfma_f32_16x16x32_bf16(a.v, bfr[n], d, 0, 0, 0);
      float mx = fmaxf(fmaxf(d[0], d[1]), fmaxf(d[2], d[3]));
      o1[oidx + n * 16 + m16] = f2bf(fmaxf(mx + bias[n], 0.f));
    }
  }
}

// ---------------- conv2/conv3: kn2row implicit-GEMM MFMA, fused bias+relu+pool
// 2 batches per block; each wave = 64px x 64oc (ms=4 x ns=4).
// B-fragments come from fragment-linear w2t/w3t: one coalesced 1KB load per frag.
template <int IC, int ICP, int OCT, int OCB, int INW, int POOLW>
__global__ __launch_bounds__(256) void conv_mfma(const ushort* __restrict__ in,
                                                 const ushort* __restrict__ wt,
                                                 const float* __restrict__ bias,
                                                 ushort* __restrict__ out) {
  constexpr int NPIX = 144;  // 12*12 input tile
  constexpr int PSTRIDE = OCB + 8;
  constexpr int LDSA = 2 * NPIX * ICP;
  constexpr int LDSP = 2 * 64 * PSTRIDE;
  constexpr int LDSN = (LDSA > LDSP) ? LDSA : LDSP;
  constexpr int NKS = IC / 32;
  constexpr int NFRAG = OCT / 16;
  __shared__ ushort sm[LDSN];
  const int tid = threadIdx.x;
  const int wid = tid >> 6, lane = tid & 63;
  const int m16 = lane & 15, qd = lane >> 4;
  const int bh = wid >> 1, og = wid & 1;
  constexpr int OCSPLIT = OCT / OCB;
  const int bpair = blockIdx.z / OCSPLIT;
  const int ocblk = (blockIdx.z % OCSPLIT) * OCB;
  const int b0 = bpair * 2;
  const int ty = blockIdx.y, tx = blockIdx.x;
  {
    constexpr int C8 = IC / 8;
    for (int i = tid; i < 2 * NPIX * C8; i += 256) {
      int bb = i / (NPIX * C8), rem = i % (NPIX * C8);
      int px = rem / C8, c8 = rem % C8;
      int gy = ty * 8 + px / 12, gx = tx * 8 + px % 12;
      uint4 v = *(const uint4*)(in + (((size_t)(b0 + bb) * INW + gy) * INW + gx) * IC + c8 * 8);
      *(uint4*)&sm[(bb * NPIX + px) * ICP + c8 * 8] = v;
    }
  }
  __syncthreads();
  f32x4 acc[4][4];
#pragma unroll
  for (int i = 0; i < 4; i++)
#pragma unroll
    for (int j = 0; j < 4; j++) acc[i][j] = (f32x4){0.f, 0.f, 0.f, 0.f};
  int aoff[4];
#pragma unroll
  for (int ms = 0; ms < 4; ms++) {
    int p = ms * 16 + m16;
    aoff[ms] = (bh * NPIX + (p >> 3) * 12 + (p & 7)) * ICP + qd * 8;
  }
  const int fo0 = (ocblk >> 4) + og * 4;
  for (int ky = 0; ky < 5; ky++) {
#pragma unroll
    for (int kx = 0; kx < 5; kx++) {
      const int koff = (ky * 12 + kx) * ICP;
      const ushort* wkp = wt + (((size_t)(ky * 5 + kx) * NFRAG + fo0) * NKS) * 512 + lane * 8;
#pragma unroll
      for (int ks = 0; ks < NKS; ks++) {
        short8 afr[4], bfr[4];
#pragma unroll
        for (int ms = 0; ms < 4; ms++)
          afr[ms] = *(const short8*)&sm[aoff[ms] + koff + ks * 32];
#pragma unroll
        for (int ns = 0; ns < 4; ns++)
          bfr[ns] = *(const short8*)(wkp + (ns * NKS + ks) * 512);
#pragma unroll
        for (int ms = 0; ms < 4; ms++)
#pragma unroll
          for (int ns = 0; ns < 4; ns++)
            acc[ms][ns] = __builtin_amdgcn_mfma_f32_16x16x32_bf16(afr[ms], bfr[ns], acc[ms][ns], 0, 0, 0);
      }
    }
  }
  __syncthreads();
#pragma unroll
  for (int ms = 0; ms < 4; ms++)
#pragma unroll
    for (int ns = 0; ns < 4; ns++) {
      int ocl = og * 64 + ns * 16 + m16;
      float bv = bias[ocblk + ocl];
#pragma unroll
      for (int r = 0; r < 4; r++) {
        int p = ms * 16 + qd * 4 + r;
        sm[(bh * 64 + p) * PSTRIDE + ocl] = f2bf(fmaxf(acc[ms][ns][r] + bv, 0.f));
      }
    }
  __syncthreads();
  constexpr int OC2 = OCB / 2;
  const int oc2 = tid % OC2, pst = tid / OC2;
  for (int pp = pst; pp < 32; pp += 256 / OC2) {
    int bb = pp >> 4, pl = pp & 15;
    int ppy = pl >> 2, ppx = pl & 3;
    int p00 = (ppy * 2) * 8 + ppx * 2;
    int oc = oc2 * 2;
    int base = bb * 64 * PSTRIDE;
    uint32_t v0 = *(const uint32_t*)&sm[base + p00 * PSTRIDE + oc];
    uint32_t v1 = *(const uint32_t*)&sm[base + (p00 + 1) * PSTRIDE + oc];
    uint32_t v2 = *(const uint32_t*)&sm[base + (p00 + 8) * PSTRIDE + oc];
    uint32_t v3 = *(const uint32_t*)&sm[base + (p00 + 9) * PSTRIDE + oc];
    float a0 = fmaxf(fmaxf(bf2f(v0 & 0xffff), bf2f(v1 & 0xffff)),
                     fmaxf(bf2f(v2 & 0xffff), bf2f(v3 & 0xffff)));
    float a1 = fmaxf(fmaxf(bf2f(v0 >> 16), bf2f(v1 >> 16)),
                     fmaxf(bf2f(v2 >> 16), bf2f(v3 >> 16)));
    uint32_t packed = ((uint32_t)f2bf(a1) << 16) | (uint32_t)f2bf(a0);
    int gy = ty * 4 + ppy, gx = tx * 4 + ppx;
    *(uint32_t*)&out[(((size_t)(b0 + bb) * POOLW + gy) * POOLW + gx) * OCT + ocblk + oc] = packed;
  }
}

// ---------------- transpose o3 NHWC -> NCHW-flat (for FC), bf16
__global__ void transpose_o3(const ushort* __restrict__ o3, ushort* __restrict__ flatT) {
  __shared__ ushort t[32][33];
  const int b = blockIdx.z;
  const int n0 = blockIdx.x * 32, c0 = blockIdx.y * 32;
  const int tid = threadIdx.x;
  {
    int cl = tid & 31, r = tid >> 5;
    for (int i = 0; i < 4; i++) {
      int nl = r + i * 8;
      t[nl][cl] = o3[((size_t)b * 576 + n0 + nl) * 256 + c0 + cl];
    }
  }
  __syncthreads();
  {
    int nl = tid & 31, r = tid >> 5;
    for (int i = 0; i < 4; i++) {
      int cl = r + i * 8;
      flatT[(size_t)b * 147456 + (c0 + cl) * 576 + n0 + nl] = t[nl][cl];
    }
  }
}

// ---------------- FC: g[16][512] = flat @ fcw^T, MFMA; A coalesced from flatT.
__global__ void fc_mfma(const ushort* __restrict__ flatT, const float* __restrict__ fcw,
                        float* __restrict__ g) {
  const int tid = threadIdx.x;
  const int wid = tid >> 6, lane = tid & 63;
  const int m16 = lane & 15, qd = lane >> 4;
  const int jt = blockIdx.y * 256 + wid * 64;
  const int K0 = blockIdx.x * 576;
  f32x4 acc[4];
#pragma unroll
  for (int f = 0; f < 4; f++) acc[f] = (f32x4){0.f, 0.f, 0.f, 0.f};
  const ushort* ap = flatT + (size_t)m16 * 147456 + K0 + qd * 8;
  const float* bp = fcw + (size_t)(jt + m16) * 147456 + K0 + qd * 8;
#pragma unroll 2
  for (int ks = 0; ks < 18; ks++) {
    short8 a = *(const short8*)(ap + ks * 32);
#pragma unroll
    for (int f = 0; f < 4; f++) {
      const float* bpf = bp + (size_t)f * 16 * 147456 + ks * 32;
      float4 b0 = *(const float4*)bpf;
      float4 b1 = *(const float4*)(bpf + 4);
      short8 bb;
      bb[0] = (short)f2bf(b0.x); bb[1] = (short)f2bf(b0.y);
      bb[2] = (short)f2bf(b0.z); bb[3] = (short)f2bf(b0.w);
      bb[4] = (short)f2bf(b1.x); bb[5] = (short)f2bf(b1.y);
      bb[6] = (short)f2bf(b1.z); bb[7] = (short)f2bf(b1.w);
      acc[f] = __builtin_amdgcn_mfma_f32_16x16x32_bf16(a, bb, acc[f], 0, 0, 0);
    }
  }
  const int brow = qd * 4;
#pragma unroll
  for (int f = 0; f < 4; f++)
#pragma unroll
    for (int r = 0; r < 4; r++)
      atomicAdd(&g[(brow + r) * 512 + jt + f * 16 + m16], acc[f][r]);
}

// ---------------- qcalc: q[16][448] = [aw1;aw2;aw3] @ (g+fcb) + [ab1;ab2;ab3]
// one block per batch; kills the per-block redundant prelude in scores_all.
__global__ __launch_bounds__(256) void qcalc(const float* __restrict__ g,
                                             const float* __restrict__ fcb,
                                             const float* __restrict__ aw1, const float* __restrict__ ab1,
                                             const float* __restrict__ aw2, const float* __restrict__ ab2,
                                             const float* __restrict__ aw3, const float* __restrict__ ab3,
                                             float* __restrict__ q) {
  const int b = blockIdx.x, tid = threadIdx.x;
  __shared__ float gs[512];
  for (int i = tid; i < 512; i += 256) gs[i] = g[b * 512 + i] + fcb[i];
  __syncthreads();
  for (int c = tid; c < 448; c += 256) {
    const float* ar;
    float acc;
    if (c < 64)       { ar = aw1 + (size_t)c * 512;         acc = ab1[c]; }
    else if (c < 192) { ar = aw2 + (size_t)(c - 64) * 512;  acc = ab2[c - 64]; }
    else              { ar = aw3 + (size_t)(c - 192) * 512; acc = ab3[c - 192]; }
#pragma unroll 4
    for (int j = 0; j < 512; j += 4) {
      float4 a4 = *(const float4*)(ar + j);
      acc += a4.x * gs[j] + a4.y * gs[j + 1] + a4.z * gs[j + 2] + a4.w * gs[j + 3];
    }
    q[b * 448 + c] = acc;
  }
}

// ---------------- scores (all heads): dot rows against precomputed q
template <int C, int COFF>
__device__ __forceinline__ void score_head(const ushort* __restrict__ f,
                                           const float* __restrict__ q,
                                           float* __restrict__ s, int N, int nblk, int b,
                                           float* sq) {
  const int tid = threadIdx.x;
  if (tid < C) sq[tid] = q[b * 448 + COFF + tid];
  __syncthreads();
  int n = nblk * 256 + tid;
  if (n >= N) return;
  const ushort* fr = f + ((size_t)b * N + n) * C;
  float acc = 0.f;
#pragma unroll
  for (int c0 = 0; c0 < C; c0 += 8) {
    uint4 v = *(const uint4*)&fr[c0];
    uint32_t arr[4] = {v.x, v.y, v.z, v.w};
#pragma unroll
    for (int k = 0; k < 4; k++) {
      acc += bf2f(arr[k] & 0xffff) * sq[c0 + 2 * k];
      acc += bf2f(arr[k] >> 16) * sq[c0 + 2 * k + 1];
    }
  }
  s[(size_t)b * N + n] = acc;
}

__global__ void scores_all(const ushort* __restrict__ o1, const ushort* __restrict__ o2,
                           const ushort* __restrict__ o3, const float* __restrict__ q,
                           float* __restrict__ s1, float* __restrict__ s2,
                           float* __restrict__ s3) {
  __shared__ float sq[256];
  const int bx = blockIdx.x, b = blockIdx.y;
  if (bx < 46)      score_head<64, 0>(o1, q, s1, 11664, bx, b, sq);
  else if (bx < 57) score_head<128, 64>(o2, q, s2, 2704, bx - 46, b, sq);
  else              score_head<256, 192>(o3, q, s3, 576, bx - 57, b, sq);
}

// ---------------- softmax stats (all heads)
__global__ void stats_all(const float* __restrict__ s1, const float* __restrict__ s2,
                          const float* __restrict__ s3, float* __restrict__ st) {
  const int b = blockIdx.x, head = blockIdx.y, tid = threadIdx.x;
  const float* s; int N; float* stp;
  if (head == 0)      { s = s1; N = 11664; stp = st; }
  else if (head == 1) { s = s2; N = 2704;  stp = st + 32; }
  else                { s = s3; N = 576;   stp = st + 64; }
  const float* sb = s + (size_t)b * N;
  __shared__ float red[4];
  float m = -1e30f;
  for (int i = tid; i < N; i += 256) m = fmaxf(m, sb[i]);
  for (int o = 32; o; o >>= 1) m = fmaxf(m, __shfl_xor(m, o));
  if ((tid & 63) == 0) red[tid >> 6] = m;
  __syncthreads();
  m = fmaxf(fmaxf(red[0], red[1]), fmaxf(red[2], red[3]));
  __syncthreads();
  float l = 0.f;
  for (int i = tid; i < N; i += 256) l += __expf(sb[i] - m);
  for (int o = 32; o; o >>= 1) l += __shfl_xor(l, o);
  if ((tid & 63) == 0) red[tid >> 6] = l;
  __syncthreads();
  if (tid == 0) { stp[b * 2] = m; stp[b * 2 + 1] = red[0] + red[1] + red[2] + red[3]; }
}

// ---------------- weighted sum (all heads)
template <int C, int COFF, int CHUNK>
__device__ __forceinline__ void wsum_head(const ushort* __restrict__ f,
                                          const float* __restrict__ s,
                                          const float* __restrict__ st,
                                          float* __restrict__ out, int N, int nblk, int b) {
  const int tid = threadIdx.x;
  constexpr int S = 256 / C;
  const int c = tid % C, sub = tid / C;
  const float m = st[b * 2], rl = 1.f / st[b * 2 + 1];
  const float* sb = s + (size_t)b * N;
  const ushort* fb = f + (size_t)b * N * C;
  int n0 = nblk * CHUNK;
  int n1 = n0 + CHUNK; if (n1 > N) n1 = N;
  float acc = 0.f;
  for (int n = n0 + sub; n < n1; n += S) {
    float w = __expf(sb[n] - m);
    acc += w * bf2f(fb[(size_t)n * C + c]);
  }
  atomicAdd(&out[b * 448 + COFF + c], acc * rl);
}

__global__ void wsum_all(const ushort* __restrict__ o1, const ushort* __restrict__ o2,
                         const ushort* __restrict__ o3, const float* __restrict__ s1,
                         const float* __restrict__ s2, const float* __restrict__ s3,
                         const float* __restrict__ st, float* __restrict__ out) {
  const int bx = blockIdx.x, b = blockIdx.y;
  if (bx < 24)      wsum_head<64, 0, 486>(o1, s1, st, out, 11664, bx, b);
  else if (bx < 40) wsum_head<128, 64, 169>(o2, s2, st + 32, out, 2704, bx - 24, b);
  else              wsum_head<256, 192, 72>(o3, s3, st + 64, out, 576, bx - 40, b);
}

extern "C" void kernel_launch(void* const* d_in, const int* in_sizes, int n_in,
                              void* d_out, int out_size, void* d_ws, size_t ws_size,
                              hipStream_t stream) {
  const float* x   = (const float*)d_in[0];
  const float* w1  = (const float*)d_in[1];
  const float* b1  = (const float*)d_in[2];
  const float* w2  = (const float*)d_in[3];
  const float* b2  = (const float*)d_in[4];
  const float* w3  = (const float*)d_in[5];
  const float* b3  = (const float*)d_in[6];
  const float* fcw = (const float*)d_in[7];
  const float* fcb = (const float*)d_in[8];
  const float* aw1 = (const float*)d_in[9];
  const float* ab1 = (const float*)d_in[10];
  const float* aw2 = (const float*)d_in[11];
  const float* ab2 = (const float*)d_in[12];
  const float* aw3 = (const float*)d_in[13];
  const float* ab3 = (const float*)d_in[14];
  float* out = (float*)d_out;
  char* ws = (char*)d_ws;

  ushort* o1    = (ushort*)(ws + 0);         // 23887872
  ushort* o2    = (ushort*)(ws + 23887872);  // 11075584
  ushort* o3    = (ushort*)(ws + 34963456);  // 4718592
  ushort* flatT = (ushort*)(ws + 39682048);  // 4718592
  ushort* w2t   = (ushort*)(ws + 44400640);  // 409600
  ushort* w3t   = (ushort*)(ws + 44810240);  // 1638400
  float*  g     = (float*)(ws + 46448640);   // 32768
  float*  s1    = (float*)(ws + 46510080);   // 746496
  float*  s2    = (float*)(ws + 47256576);   // 173056
  float*  s3    = (float*)(ws + 47429632);   // 36864
  float*  st    = (float*)(ws + 47466496);   // 384
  float*  q     = (float*)(ws + 47466880);   // 28672

  prelude_k<<<4497, 256, 0, stream>>>(x, w1, b1, w2, w3, o1, w2t, w3t, g, out);
  conv_mfma<64, 72, 128, 128, 108, 52><<<dim3(13, 13, 8), 256, 0, stream>>>(o1, w2t, b2, o2);
  conv_mfma<128, 136, 256, 128, 52, 24><<<dim3(6, 6, 16), 256, 0, stream>>>(o2, w3t, b3, o3);
  transpose_o3<<<dim3(18, 8, 16), 256, 0, stream>>>(o3, flatT);
  fc_mfma<<<dim3(256, 2), 256, 0, stream>>>(flatT, fcw, g);
  qcalc<<<16, 256, 0, stream>>>(g, fcb, aw1, ab1, aw2, ab2, aw3, ab3, q);
  scores_all<<<dim3(60, 16), 256, 0, stream>>>(o1, o2, o3, q, s1, s2, s3);
  stats_all<<<dim3(16, 3), 256, 0, stream>>>(s1, s2, s3, st);
  wsum_all<<<dim3(48, 16), 256, 0, stream>>>(o1, o2, o3, s1, s2, s3, st, out);
}

// Round 3
// 652.023 us; speedup vs baseline: 1.3293x; 1.0902x over previous
//
#include <hip/hip_runtime.h>
#include <cstdint>

typedef __attribute__((ext_vector_type(8))) short short8;
typedef __attribute__((ext_vector_type(4))) float f32x4;

__device__ __forceinline__ ushort f2bf(float f) {
  union { float f; uint32_t u; } v; v.f = f;
  uint32_t u = v.u;
  return (ushort)((u + 0x7fffu + ((u >> 16) & 1u)) >> 16);  // RNE
}
__device__ __forceinline__ float bf2f(ushort h) {
  union { uint32_t u; float f; } v; v.u = ((uint32_t)h) << 16;
  return v.f;
}

// ---------------- prelude: conv1 (im2col MFMA) + weight transforms + zero g/out.
// blocks [0,1296): conv1; [1296,4496): w2t/w3t transform; 4496: zero g+out.
// w2t/w3t are written in MFMA-fragment-linear order:
//   idx = (((kpos*(OCT/16) + fo)*(IC/32)) + ks)*512 + lane*8 + j
//   value = w[oc = fo*16 + (lane&15)][ic = ks*32 + (lane>>4)*8 + j][kpos]
// so conv_mfma's B-fragment load is one wave-coalesced 1KB read.
__global__ __launch_bounds__(256) void prelude_k(
    const float* __restrict__ x, const float* __restrict__ w1, const float* __restrict__ b1,
    const float* __restrict__ w2, const float* __restrict__ w3,
    ushort* __restrict__ o1, ushort* __restrict__ w2t, ushort* __restrict__ w3t,
    float* __restrict__ g, float* __restrict__ out) {
  __shared__ ushort sb[28 * 29];
  const int tid = threadIdx.x;
  const int bx = blockIdx.x;
  if (bx >= 1296) {
    if (bx < 4496) {
      int idx = (bx - 1296) * 256 + tid;
      if (idx < 204800) {  // 25 kpos * 8 frags * 2 ks * 512
        int j = idx & 7, lane = (idx >> 3) & 63, ks = (idx >> 9) & 1,
            fo = (idx >> 10) & 7, kpos = idx >> 13;
        int oc = fo * 16 + (lane & 15);
        int ic = ks * 32 + (lane >> 4) * 8 + j;
        w2t[idx] = f2bf(w2[((size_t)oc * 64 + ic) * 25 + kpos]);
      }
      {  // 25 kpos * 16 frags * 4 ks * 512 = 819200
        int j = idx & 7, lane = (idx >> 3) & 63, ks = (idx >> 9) & 3,
            fo = (idx >> 11) & 15, kpos = idx >> 15;
        int oc = fo * 16 + (lane & 15);
        int ic = ks * 32 + (lane >> 4) * 8 + j;
        w3t[idx] = f2bf(w3[((size_t)oc * 128 + ic) * 25 + kpos]);
      }
    } else {
      for (int i = tid; i < 8192; i += 256) g[i] = 0.f;
      for (int i = tid; i < 7168; i += 256) out[i] = 0.f;
    }
    return;
  }
  // conv1: tile 24x24 conv outputs (28x28 input), pooled 12x12x64 out
  const int b = bx / 81, rem = bx % 81, ty = rem / 9, tx = rem % 9;
  for (int i = tid; i < 784; i += 256) {
    int iy = i / 28, ix = i % 28;
    sb[iy * 29 + ix] = f2bf(x[((size_t)b * 220 + ty * 24 + iy) * 220 + tx * 24 + ix]);
  }
  __syncthreads();
  const int lane = tid & 63, wid = tid >> 6;
  const int m16 = lane & 15, qd = lane >> 4;
  short8 bfr[4];
#pragma unroll
  for (int n = 0; n < 4; n++) {
    union { ushort u[8]; short8 v; } t;
#pragma unroll
    for (int j = 0; j < 8; j++) {
      int k = qd * 8 + j;
      int kc = k < 25 ? k : 0;
      ushort val = f2bf(w1[(n * 16 + m16) * 25 + kc]);
      t.u[j] = (k < 25) ? val : (ushort)0;
    }
    bfr[n] = t.v;
  }
  int offs[8];
#pragma unroll
  for (int j = 0; j < 8; j++) {
    int k = qd * 8 + j;
    int kc = k < 25 ? k : 24;  // k>=25: B is zero, value irrelevant
    offs[j] = (kc / 5) * 29 + (kc % 5);
  }
  float bias[4];
#pragma unroll
  for (int n = 0; n < 4; n++) bias[n] = b1[n * 16 + m16];
  for (int gg = 0; gg < 9; gg++) {
    int gr = wid * 9 + gg;
    int wglob = gr * 4 + (m16 >> 2);
    int wy = wglob / 12, wx = wglob % 12;
    int py = wy * 2 + ((m16 >> 1) & 1), px = wx * 2 + (m16 & 1);
    int base = py * 29 + px;
    union { ushort u[8]; short8 v; } a;
#pragma unroll
    for (int j = 0; j < 8; j++) a.u[j] = sb[base + offs[j]];
    int wgd = gr * 4 + qd;
    int gy = ty * 12 + wgd / 12, gx = tx * 12 + wgd % 12;
    size_t oidx = (((size_t)b * 108 + gy) * 108 + gx) * 64;
#pragma unroll
    for (int n = 0; n < 4; n++) {
      f32x4 d = (f32x4){0.f, 0.f, 0.f, 0.f};
      d = __builtin_amdgcn_mfma_f32_16x16x32_bf16(a.v, bfr[n], d, 0, 0, 0);
      float mx = fmaxf(fmaxf(d[0], d[1]), fmaxf(d[2], d[3]));
      o1[oidx + n * 16 + m16] = f2bf(fmaxf(mx + bias[n], 0.f));
    }
  }
}

// ---------------- conv2/conv3: kn2row implicit-GEMM MFMA, fused bias+relu+pool
// WOC waves split the full OCT; NB = 4/WOC batches per block.
// conv2: WOC=2, NB=2 (identical mapping to prior round).
// conv3: WOC=4, NB=1 -> LDS 39KB -> 3 blocks/CU -> 576 blocks fit one round.
template <int IC, int ICP, int OCT, int WOC, int INW, int POOLW>
__global__ __launch_bounds__(256, 3) void conv_mfma(const ushort* __restrict__ in,
                                                    const ushort* __restrict__ wt,
                                                    const float* __restrict__ bias,
                                                    ushort* __restrict__ out) {
  constexpr int NB = 4 / WOC;
  constexpr int NPIX = 144;  // 12*12 input tile
  constexpr int PSTRIDE = OCT + 8;
  constexpr int LDSA = NB * NPIX * ICP;
  constexpr int LDSP = NB * 64 * PSTRIDE;
  constexpr int LDSN = (LDSA > LDSP) ? LDSA : LDSP;
  constexpr int NKS = IC / 32;
  constexpr int NFRAG = OCT / 16;
  __shared__ ushort sm[LDSN];
  const int tid = threadIdx.x;
  const int wid = tid >> 6, lane = tid & 63;
  const int m16 = lane & 15, qd = lane >> 4;
  const int bh = wid / WOC, og = wid % WOC;
  const int b0 = blockIdx.z * NB;
  const int ty = blockIdx.y, tx = blockIdx.x;
  {
    constexpr int C8 = IC / 8;
    for (int i = tid; i < NB * NPIX * C8; i += 256) {
      int bb = i / (NPIX * C8), rem = i % (NPIX * C8);
      int px = rem / C8, c8 = rem % C8;
      int gy = ty * 8 + px / 12, gx = tx * 8 + px % 12;
      uint4 v = *(const uint4*)(in + (((size_t)(b0 + bb) * INW + gy) * INW + gx) * IC + c8 * 8);
      *(uint4*)&sm[(bb * NPIX + px) * ICP + c8 * 8] = v;
    }
  }
  __syncthreads();
  f32x4 acc[4][4];
#pragma unroll
  for (int i = 0; i < 4; i++)
#pragma unroll
    for (int j = 0; j < 4; j++) acc[i][j] = (f32x4){0.f, 0.f, 0.f, 0.f};
  int aoff[4];
#pragma unroll
  for (int ms = 0; ms < 4; ms++) {
    int p = ms * 16 + m16;
    aoff[ms] = (bh * NPIX + (p >> 3) * 12 + (p & 7)) * ICP + qd * 8;
  }
  const int fo0 = og * 4;
  for (int ky = 0; ky < 5; ky++) {
#pragma unroll
    for (int kx = 0; kx < 5; kx++) {
      const int koff = (ky * 12 + kx) * ICP;
      const ushort* wkp = wt + (((size_t)(ky * 5 + kx) * NFRAG + fo0) * NKS) * 512 + lane * 8;
#pragma unroll
      for (int ks = 0; ks < NKS; ks++) {
        short8 afr[4], bfr[4];
#pragma unroll
        for (int ms = 0; ms < 4; ms++)
          afr[ms] = *(const short8*)&sm[aoff[ms] + koff + ks * 32];
#pragma unroll
        for (int ns = 0; ns < 4; ns++)
          bfr[ns] = *(const short8*)(wkp + (ns * NKS + ks) * 512);
#pragma unroll
        for (int ms = 0; ms < 4; ms++)
#pragma unroll
          for (int ns = 0; ns < 4; ns++)
            acc[ms][ns] = __builtin_amdgcn_mfma_f32_16x16x32_bf16(afr[ms], bfr[ns], acc[ms][ns], 0, 0, 0);
      }
    }
  }
  __syncthreads();
#pragma unroll
  for (int ms = 0; ms < 4; ms++)
#pragma unroll
    for (int ns = 0; ns < 4; ns++) {
      int ocl = og * 64 + ns * 16 + m16;
      float bv = bias[ocl];
#pragma unroll
      for (int r = 0; r < 4; r++) {
        int p = ms * 16 + qd * 4 + r;
        sm[(bh * 64 + p) * PSTRIDE + ocl] = f2bf(fmaxf(acc[ms][ns][r] + bv, 0.f));
      }
    }
  __syncthreads();
  constexpr int OC2 = OCT / 2;
  const int oc2 = tid % OC2, pst = tid / OC2;
  for (int pp = pst; pp < NB * 16; pp += 256 / OC2) {
    int bb = pp >> 4, pl = pp & 15;
    int ppy = pl >> 2, ppx = pl & 3;
    int p00 = (ppy * 2) * 8 + ppx * 2;
    int oc = oc2 * 2;
    int base = bb * 64 * PSTRIDE;
    uint32_t v0 = *(const uint32_t*)&sm[base + p00 * PSTRIDE + oc];
    uint32_t v1 = *(const uint32_t*)&sm[base + (p00 + 1) * PSTRIDE + oc];
    uint32_t v2 = *(const uint32_t*)&sm[base + (p00 + 8) * PSTRIDE + oc];
    uint32_t v3 = *(const uint32_t*)&sm[base + (p00 + 9) * PSTRIDE + oc];
    float a0 = fmaxf(fmaxf(bf2f(v0 & 0xffff), bf2f(v1 & 0xffff)),
                     fmaxf(bf2f(v2 & 0xffff), bf2f(v3 & 0xffff)));
    float a1 = fmaxf(fmaxf(bf2f(v0 >> 16), bf2f(v1 >> 16)),
                     fmaxf(bf2f(v2 >> 16), bf2f(v3 >> 16)));
    uint32_t packed = ((uint32_t)f2bf(a1) << 16) | (uint32_t)f2bf(a0);
    int gy = ty * 4 + ppy, gx = tx * 4 + ppx;
    *(uint32_t*)&out[(((size_t)(b0 + bb) * POOLW + gy) * POOLW + gx) * OCT + oc] = packed;
  }
}

// ---------------- transpose o3 NHWC -> NCHW-flat (for FC), bf16
__global__ void transpose_o3(const ushort* __restrict__ o3, ushort* __restrict__ flatT) {
  __shared__ ushort t[32][33];
  const int b = blockIdx.z;
  const int n0 = blockIdx.x * 32, c0 = blockIdx.y * 32;
  const int tid = threadIdx.x;
  {
    int cl = tid & 31, r = tid >> 5;
    for (int i = 0; i < 4; i++) {
      int nl = r + i * 8;
      t[nl][cl] = o3[((size_t)b * 576 + n0 + nl) * 256 + c0 + cl];
    }
  }
  __syncthreads();
  {
    int nl = tid & 31, r = tid >> 5;
    for (int i = 0; i < 4; i++) {
      int cl = r + i * 8;
      flatT[(size_t)b * 147456 + (c0 + cl) * 576 + n0 + nl] = t[nl][cl];
    }
  }
}

// ---------------- FC: g[16][512] = flat @ fcw^T, MFMA; A coalesced from flatT.
// grid (384,2) = 768 blocks -> 3 blocks/CU, one full round; deeper HBM pipelining.
__global__ void fc_mfma(const ushort* __restrict__ flatT, const float* __restrict__ fcw,
                        float* __restrict__ g) {
  const int tid = threadIdx.x;
  const int wid = tid >> 6, lane = tid & 63;
  const int m16 = lane & 15, qd = lane >> 4;
  const int jt = blockIdx.y * 256 + wid * 64;
  const int K0 = blockIdx.x * 384;
  f32x4 acc[4];
#pragma unroll
  for (int f = 0; f < 4; f++) acc[f] = (f32x4){0.f, 0.f, 0.f, 0.f};
  const ushort* ap = flatT + (size_t)m16 * 147456 + K0 + qd * 8;
  const float* bp = fcw + (size_t)(jt + m16) * 147456 + K0 + qd * 8;
#pragma unroll 2
  for (int ks = 0; ks < 12; ks++) {
    short8 a = *(const short8*)(ap + ks * 32);
#pragma unroll
    for (int f = 0; f < 4; f++) {
      const float* bpf = bp + (size_t)f * 16 * 147456 + ks * 32;
      float4 b0 = *(const float4*)bpf;
      float4 b1 = *(const float4*)(bpf + 4);
      short8 bb;
      bb[0] = (short)f2bf(b0.x); bb[1] = (short)f2bf(b0.y);
      bb[2] = (short)f2bf(b0.z); bb[3] = (short)f2bf(b0.w);
      bb[4] = (short)f2bf(b1.x); bb[5] = (short)f2bf(b1.y);
      bb[6] = (short)f2bf(b1.z); bb[7] = (short)f2bf(b1.w);
      acc[f] = __builtin_amdgcn_mfma_f32_16x16x32_bf16(a, bb, acc[f], 0, 0, 0);
    }
  }
  const int brow = qd * 4;
#pragma unroll
  for (int f = 0; f < 4; f++)
#pragma unroll
    for (int r = 0; r < 4; r++)
      atomicAdd(&g[(brow + r) * 512 + jt + f * 16 + m16], acc[f][r]);
}

// ---------------- qcalc: q[16][448] = [aw1;aw2;aw3] @ (g+fcb) + [ab1;ab2;ab3]
__global__ __launch_bounds__(256) void qcalc(const float* __restrict__ g,
                                             const float* __restrict__ fcb,
                                             const float* __restrict__ aw1, const float* __restrict__ ab1,
                                             const float* __restrict__ aw2, const float* __restrict__ ab2,
                                             const float* __restrict__ aw3, const float* __restrict__ ab3,
                                             float* __restrict__ q) {
  const int b = blockIdx.x, tid = threadIdx.x;
  const int cpart = blockIdx.y;  // 2-way split of the 448 columns
  __shared__ float gs[512];
  for (int i = tid; i < 512; i += 256) gs[i] = g[b * 512 + i] + fcb[i];
  __syncthreads();
  for (int c = cpart * 224 + tid; c < cpart * 224 + 224; c += 256) {
    const float* ar;
    float acc;
    if (c < 64)       { ar = aw1 + (size_t)c * 512;         acc = ab1[c]; }
    else if (c < 192) { ar = aw2 + (size_t)(c - 64) * 512;  acc = ab2[c - 64]; }
    else              { ar = aw3 + (size_t)(c - 192) * 512; acc = ab3[c - 192]; }
#pragma unroll 4
    for (int j = 0; j < 512; j += 4) {
      float4 a4 = *(const float4*)(ar + j);
      acc += a4.x * gs[j] + a4.y * gs[j + 1] + a4.z * gs[j + 2] + a4.w * gs[j + 3];
    }
    q[b * 448 + c] = acc;
  }
}

// ---------------- scores (all heads): dot rows against precomputed q
template <int C, int COFF>
__device__ __forceinline__ void score_head(const ushort* __restrict__ f,
                                           const float* __restrict__ q,
                                           float* __restrict__ s, int N, int nblk, int b,
                                           float* sq) {
  const int tid = threadIdx.x;
  if (tid < C) sq[tid] = q[b * 448 + COFF + tid];
  __syncthreads();
  int n = nblk * 256 + tid;
  if (n >= N) return;
  const ushort* fr = f + ((size_t)b * N + n) * C;
  float acc = 0.f;
#pragma unroll
  for (int c0 = 0; c0 < C; c0 += 8) {
    uint4 v = *(const uint4*)&fr[c0];
    uint32_t arr[4] = {v.x, v.y, v.z, v.w};
#pragma unroll
    for (int k = 0; k < 4; k++) {
      acc += bf2f(arr[k] & 0xffff) * sq[c0 + 2 * k];
      acc += bf2f(arr[k] >> 16) * sq[c0 + 2 * k + 1];
    }
  }
  s[(size_t)b * N + n] = acc;
}

__global__ void scores_all(const ushort* __restrict__ o1, const ushort* __restrict__ o2,
                           const ushort* __restrict__ o3, const float* __restrict__ q,
                           float* __restrict__ s1, float* __restrict__ s2,
                           float* __restrict__ s3) {
  __shared__ float sq[256];
  const int bx = blockIdx.x, b = blockIdx.y;
  if (bx < 46)      score_head<64, 0>(o1, q, s1, 11664, bx, b, sq);
  else if (bx < 57) score_head<128, 64>(o2, q, s2, 2704, bx - 46, b, sq);
  else              score_head<256, 192>(o3, q, s3, 576, bx - 57, b, sq);
}

// ---------------- softmax stats (all heads)
__global__ void stats_all(const float* __restrict__ s1, const float* __restrict__ s2,
                          const float* __restrict__ s3, float* __restrict__ st) {
  const int b = blockIdx.x, head = blockIdx.y, tid = threadIdx.x;
  const float* s; int N; float* stp;
  if (head == 0)      { s = s1; N = 11664; stp = st; }
  else if (head == 1) { s = s2; N = 2704;  stp = st + 32; }
  else                { s = s3; N = 576;   stp = st + 64; }
  const float* sb = s + (size_t)b * N;
  __shared__ float red[4];
  float m = -1e30f;
  for (int i = tid; i < N; i += 256) m = fmaxf(m, sb[i]);
  for (int o = 32; o; o >>= 1) m = fmaxf(m, __shfl_xor(m, o));
  if ((tid & 63) == 0) red[tid >> 6] = m;
  __syncthreads();
  m = fmaxf(fmaxf(red[0], red[1]), fmaxf(red[2], red[3]));
  __syncthreads();
  float l = 0.f;
  for (int i = tid; i < N; i += 256) l += __expf(sb[i] - m);
  for (int o = 32; o; o >>= 1) l += __shfl_xor(l, o);
  if ((tid & 63) == 0) red[tid >> 6] = l;
  __syncthreads();
  if (tid == 0) { stp[b * 2] = m; stp[b * 2 + 1] = red[0] + red[1] + red[2] + red[3]; }
}

// ---------------- weighted sum (all heads)
// v2: exp computed ONCE per n into LDS (kills C-fold transcendental redundancy),
// 2-channel uint32 loads, LDS-reduced partials, C global atomics per block.
template <int C, int COFF, int CHUNK>
__device__ __forceinline__ void wsum_head(const ushort* __restrict__ f,
                                          const float* __restrict__ s,
                                          const float* __restrict__ st,
                                          float* __restrict__ out, int N, int nblk, int b,
                                          float* ws, float* os) {
  const int tid = threadIdx.x;
  const float m = st[b * 2], rl = 1.f / st[b * 2 + 1];
  const float* sb = s + (size_t)b * N;
  const ushort* fb = f + (size_t)b * N * C;
  const int n0 = nblk * CHUNK;
  int n1 = n0 + CHUNK; if (n1 > N) n1 = N;
  const int L = n1 - n0;
  for (int i = tid; i < L; i += 256) ws[i] = __expf(sb[n0 + i] - m);
  for (int i = tid; i < C; i += 256) os[i] = 0.f;
  __syncthreads();
  constexpr int C2 = C / 2;
  constexpr int S2 = 256 / C2;
  const int c2 = tid % C2, sub = tid / C2;
  float a0 = 0.f, a1 = 0.f;
  for (int i = sub; i < L; i += S2) {
    uint32_t v = *(const uint32_t*)&fb[(size_t)(n0 + i) * C + c2 * 2];
    float w = ws[i];
    a0 += w * bf2f(v & 0xffff);
    a1 += w * bf2f(v >> 16);
  }
  atomicAdd(&os[c2 * 2], a0);
  atomicAdd(&os[c2 * 2 + 1], a1);
  __syncthreads();
  for (int i = tid; i < C; i += 256) atomicAdd(&out[b * 448 + COFF + i], os[i] * rl);
}

__global__ void wsum_all(const ushort* __restrict__ o1, const ushort* __restrict__ o2,
                         const ushort* __restrict__ o3, const float* __restrict__ s1,
                         const float* __restrict__ s2, const float* __restrict__ s3,
                         const float* __restrict__ st, float* __restrict__ out) {
  __shared__ float ws[488];
  __shared__ float os[256];
  const int bx = blockIdx.x, b = blockIdx.y;
  if (bx < 24)      wsum_head<64, 0, 486>(o1, s1, st, out, 11664, bx, b, ws, os);
  else if (bx < 40) wsum_head<128, 64, 169>(o2, s2, st + 32, out, 2704, bx - 24, b, ws, os);
  else              wsum_head<256, 192, 72>(o3, s3, st + 64, out, 576, bx - 40, b, ws, os);
}

extern "C" void kernel_launch(void* const* d_in, const int* in_sizes, int n_in,
                              void* d_out, int out_size, void* d_ws, size_t ws_size,
                              hipStream_t stream) {
  const float* x   = (const float*)d_in[0];
  const float* w1  = (const float*)d_in[1];
  const float* b1  = (const float*)d_in[2];
  const float* w2  = (const float*)d_in[3];
  const float* b2  = (const float*)d_in[4];
  const float* w3  = (const float*)d_in[5];
  const float* b3  = (const float*)d_in[6];
  const float* fcw = (const float*)d_in[7];
  const float* fcb = (const float*)d_in[8];
  const float* aw1 = (const float*)d_in[9];
  const float* ab1 = (const float*)d_in[10];
  const float* aw2 = (const float*)d_in[11];
  const float* ab2 = (const float*)d_in[12];
  const float* aw3 = (const float*)d_in[13];
  const float* ab3 = (const float*)d_in[14];
  float* out = (float*)d_out;
  char* ws = (char*)d_ws;

  ushort* o1    = (ushort*)(ws + 0);         // 23887872
  ushort* o2    = (ushort*)(ws + 23887872);  // 11075584
  ushort* o3    = (ushort*)(ws + 34963456);  // 4718592
  ushort* flatT = (ushort*)(ws + 39682048);  // 4718592
  ushort* w2t   = (ushort*)(ws + 44400640);  // 409600
  ushort* w3t   = (ushort*)(ws + 44810240);  // 1638400
  float*  g     = (float*)(ws + 46448640);   // 32768
  float*  s1    = (float*)(ws + 46510080);   // 746496
  float*  s2    = (float*)(ws + 47256576);   // 173056
  float*  s3    = (float*)(ws + 47429632);   // 36864
  float*  st    = (float*)(ws + 47466496);   // 384
  float*  q     = (float*)(ws + 47466880);   // 28672

  prelude_k<<<4497, 256, 0, stream>>>(x, w1, b1, w2, w3, o1, w2t, w3t, g, out);
  conv_mfma<64, 72, 128, 2, 108, 52><<<dim3(13, 13, 8), 256, 0, stream>>>(o1, w2t, b2, o2);
  conv_mfma<128, 136, 256, 4, 52, 24><<<dim3(6, 6, 16), 256, 0, stream>>>(o2, w3t, b3, o3);
  transpose_o3<<<dim3(18, 8, 16), 256, 0, stream>>>(o3, flatT);
  fc_mfma<<<dim3(384, 2), 256, 0, stream>>>(flatT, fcw, g);
  qcalc<<<dim3(16, 2), 256, 0, stream>>>(g, fcb, aw1, ab1, aw2, ab2, aw3, ab3, q);
  scores_all<<<dim3(60, 16), 256, 0, stream>>>(o1, o2, o3, q, s1, s2, s3);
  stats_all<<<dim3(16, 3), 256, 0, stream>>>(s1, s2, s3, st);
  wsum_all<<<dim3(48, 16), 256, 0, stream>>>(o1, o2, o3, s1, s2, s3, st, out);
}